// Round 9
// baseline (331.309 us; speedup 1.0000x reference)
//
#include <hip/hip_runtime.h>
#include <hip/hip_bf16.h>

typedef __attribute__((ext_vector_type(8))) short short8;
typedef __attribute__((ext_vector_type(4))) float float4v;
typedef unsigned int uint;

#define NBLK 192  // blocks for deghist/scatterbin passes

static __device__ __forceinline__ float2 up_bf2(uint v) {
    float2 r;
    r.x = __uint_as_float(v << 16);
    r.y = __uint_as_float(v & 0xffff0000u);
    return r;
}
static __device__ __forceinline__ short f2bf_bits(float x) {
    union { __hip_bfloat16 h; short s; } u;
    u.h = __float2bfloat16(x);
    return u.s;
}

// ---------------- degree + per-block bucket histogram (fused) ----------------

__global__ __launch_bounds__(256) void k_deghist(const int* __restrict__ dst, int E, int chunk,
        int shift, int nbuck, int* __restrict__ deg, int* __restrict__ histBlk) {
    __shared__ int h[256];
    h[threadIdx.x] = 0;
    __syncthreads();
    int blk = blockIdx.x;
    int e0 = blk * chunk, e1 = min(E, e0 + chunk);
    for (int e = e0 + threadIdx.x; e < e1; e += 256) {
        int d = dst[e];
        atomicAdd(&deg[d], 1);
        atomicAdd(&h[d >> shift], 1);
    }
    __syncthreads();
    if (threadIdx.x < nbuck) histBlk[threadIdx.x * NBLK + blk] = h[threadIdx.x];
}

// ---------------- single-block full scan: row_ptr = excl prefix(deg) ----------------

__global__ __launch_bounds__(1024) void k_scan(const int* __restrict__ deg,
                                               int* __restrict__ row_ptr, int n) {
    __shared__ int s[1024];
    int t = threadIdx.x;
    int per = (n + 1023) / 1024;
    int base = t * per;
    int end = min(n, base + per);
    int sum = 0;
    for (int i = base; i < end; ++i) sum += deg[i];
    s[t] = sum;
    __syncthreads();
    for (int off = 1; off < 1024; off <<= 1) {
        int v = (t >= off) ? s[t - off] : 0;
        __syncthreads();
        s[t] += v;
        __syncthreads();
    }
    int run = s[t] - sum;  // exclusive base
    for (int i = base; i < end; ++i) {
        row_ptr[i] = run;
        run += deg[i];
    }
    if (t == 1023) row_ptr[n] = s[1023];
}

// ---------------- dinv + prescaled features (fused) ----------------

__global__ void k_dinvxs(const int* __restrict__ deg, const float* __restrict__ x,
                         float* __restrict__ dinv, float* __restrict__ xs, int n) {
    int i = blockIdx.x * blockDim.x + threadIdx.x;
    if (i >= n) return;
    float di = rsqrtf((float)(deg[i] + 1));  // +1 self-loop
    dinv[i] = di;
    const float* xp = x + (size_t)i * 9;
    float* xo = xs + (size_t)i * 9;
#pragma unroll
    for (int f = 0; f < 9; ++f) xo[f] = di * xp[f];
}

// ---------------- CSR build: 2-level counting sort ----------------

__global__ __launch_bounds__(256) void k_bscan(const int* __restrict__ histBlk,
                                               const int* __restrict__ row_ptr,
                                               int shift, int* __restrict__ baseBlk) {
    __shared__ int s[256];
    int b = blockIdx.x, t = threadIdx.x;
    int v = (t < NBLK) ? histBlk[b * NBLK + t] : 0;
    s[t] = v;
    __syncthreads();
    for (int off = 1; off < 256; off <<= 1) {
        int u = (t >= off) ? s[t - off] : 0;
        __syncthreads();
        s[t] += u;
        __syncthreads();
    }
    if (t < NBLK) baseBlk[b * NBLK + t] = row_ptr[b << shift] + s[t] - v;
}

__global__ __launch_bounds__(256) void k_scatterbin(const int* __restrict__ src,
        const int* __restrict__ dst, int E, int chunk, int shift, int nbuck,
        const int* __restrict__ baseBlk, uint2* __restrict__ binned) {
    __shared__ int cur[256];
    int blk = blockIdx.x;
    if (threadIdx.x < nbuck) cur[threadIdx.x] = baseBlk[threadIdx.x * NBLK + blk];
    __syncthreads();
    int e0 = blk * chunk, e1 = min(E, e0 + chunk);
    for (int e = e0 + threadIdx.x; e < e1; e += 256) {
        int d = dst[e];
        int pos = atomicAdd(&cur[d >> shift], 1);
        binned[pos] = make_uint2((uint)src[e], (uint)d);
    }
}

// per-bucket exact scatter; cursors in LDS (no global atomics)
__global__ __launch_bounds__(256) void k_csrbuild(const uint2* __restrict__ binned,
        const int* __restrict__ row_ptr, int* __restrict__ csr, int shift, int n) {
    __shared__ int lcur[512];
    int b = blockIdx.x;
    int node0 = b << shift;
    int nodeEnd = (b + 1) << shift;
    if (nodeEnd > n) nodeEnd = n;
    int cnt = nodeEnd - node0;
    for (int i = threadIdx.x; i < cnt; i += 256) lcur[i] = row_ptr[node0 + i];
    __syncthreads();
    int lo = row_ptr[node0], hi = row_ptr[nodeEnd];
    for (int e = lo + threadIdx.x; e < hi; e += 256) {
        uint2 p = binned[e];
        int pos = atomicAdd(&lcur[(int)p.y - node0], 1);
        csr[pos] = (int)p.x;
    }
}

// ---------------- Layer 1 aggregate: aggx = dinv .* (sum_s xs[s] + xs[node]) ----------------

__global__ __launch_bounds__(256) void k_agg1(const float* __restrict__ xs,
                       const float* __restrict__ dinv,
                       const int* __restrict__ row_ptr, const int* __restrict__ csr,
                       float* __restrict__ aggx, int n) {
    int node = blockIdx.x * 16 + (threadIdx.x >> 4);
    if (node >= n) return;
    int f = threadIdx.x & 15;
    bool act = f < 9;
    float acc = act ? xs[node * 9 + f] : 0.f;  // self-loop (xs = dinv*x)
    int e0 = row_ptr[node], e1 = row_ptr[node + 1];
    int e = e0;
    for (; e + 2 <= e1; e += 2) {
        int sA = csr[e], sB = csr[e + 1];
        float xa = act ? xs[sA * 9 + f] : 0.f;
        float xb = act ? xs[sB * 9 + f] : 0.f;
        acc += xa + xb;
    }
    if (e < e1) {
        int sA = csr[e];
        acc += act ? xs[sA * 9 + f] : 0.f;
    }
    if (act) aggx[node * 9 + f] = dinv[node] * acc;
}

// ---------------- Layer 1 matmul: h1 = relu(aggx @ W1 + b1), bf16 ----------------

__global__ __launch_bounds__(256) void k_l1mm(const float* __restrict__ agg,
                       const float* __restrict__ W1,
                       const float* __restrict__ b1, __hip_bfloat16* __restrict__ h1, int n) {
    int t = blockIdx.x * blockDim.x + threadIdx.x;
    if (t >= n * 64) return;
    int node = t >> 6, j0 = (t & 63) << 3;
    const float* a = agg + node * 9;
    float av[9];
#pragma unroll
    for (int f = 0; f < 9; ++f) av[f] = a[f];
    float acc[8];
#pragma unroll
    for (int j = 0; j < 8; ++j) acc[j] = b1[j0 + j];
#pragma unroll
    for (int f = 0; f < 9; ++f)
#pragma unroll
        for (int j = 0; j < 8; ++j) acc[j] += av[f] * W1[f * 512 + j0 + j];
    short8 o;
#pragma unroll
    for (int j = 0; j < 8; ++j) o[j] = f2bf_bits(fmaxf(acc[j], 0.f));
    *reinterpret_cast<short8*>(h1 + (size_t)node * 512 + j0) = o;
}

// ---------------- Layer 2 GEMM: t2' = dinv .* (h1 @ W2), bf16 MFMA ----------------

__global__ __launch_bounds__(256, 2) void k_l2mm(const __hip_bfloat16* __restrict__ h1,
                       const float* __restrict__ W2, const float* __restrict__ dinv,
                       __hip_bfloat16* __restrict__ t2, int n, int nchunk) {
    __shared__ short bsh[64 * 64 * 8];  // 64 KB: [kb 0..63][c 0..63][j 0..7]
    int t = threadIdx.x;
    int colbase = blockIdx.y << 6;

    for (int idx = t; idx < 64 * 64; idx += 256) {
        int kb = idx >> 6, c = idx & 63;
        const float* wp = W2 + (size_t)(kb * 8) * 128 + colbase + c;
        short8 o;
#pragma unroll
        for (int j = 0; j < 8; ++j) o[j] = f2bf_bits(wp[j * 128]);
        *reinterpret_cast<short8*>(bsh + (size_t)idx * 8) = o;
    }
    __syncthreads();

    int wid = t >> 6, lane = t & 63;
    int chunk = blockIdx.x * 4 + wid;
    if (chunk >= nchunk) return;
    int r = lane & 15, quad = lane >> 4;
    int m0 = chunk << 6;

    float4v acc[4][4];
#pragma unroll
    for (int mt = 0; mt < 4; ++mt)
#pragma unroll
        for (int cg = 0; cg < 4; ++cg) acc[mt][cg] = (float4v){0, 0, 0, 0};

#pragma unroll
    for (int kt = 0; kt < 16; ++kt) {
        short8 a[4], b[4];
#pragma unroll
        for (int mt = 0; mt < 4; ++mt)
            a[mt] = *reinterpret_cast<const short8*>(
                h1 + (size_t)(m0 + mt * 16 + r) * 512 + kt * 32 + quad * 8);
#pragma unroll
        for (int cg = 0; cg < 4; ++cg)
            b[cg] = *reinterpret_cast<const short8*>(
                bsh + (size_t)(((kt * 4 + quad) * 64) + cg * 16 + r) * 8);
#pragma unroll
        for (int mt = 0; mt < 4; ++mt)
#pragma unroll
            for (int cg = 0; cg < 4; ++cg)
                acc[mt][cg] = __builtin_amdgcn_mfma_f32_16x16x32_bf16(a[mt], b[cg], acc[mt][cg], 0, 0, 0);
    }

#pragma unroll
    for (int mt = 0; mt < 4; ++mt)
#pragma unroll
        for (int i = 0; i < 4; ++i) {
            int node = m0 + mt * 16 + quad * 4 + i;
            if (node < n) {
                float di = dinv[node];
                __hip_bfloat16* op = t2 + (size_t)node * 128 + colbase + r;
#pragma unroll
                for (int cg = 0; cg < 4; ++cg)
                    op[cg * 16] = __float2bfloat16(di * acc[mt][cg][i]);
            }
        }
}

// ---------------- Layer 2 aggregate + fused layer-3 matmul ----------------
// wave per node; 8 independent 256B row reads in flight per iteration.

__global__ __launch_bounds__(256) void k_agg2(const uint* __restrict__ t2u,
                       const float* __restrict__ dinv,
                       const int* __restrict__ row_ptr, const int* __restrict__ csr,
                       const float* __restrict__ b2, const float* __restrict__ W3,
                       float2* __restrict__ t3, int n) {
    int node = blockIdx.x * 4 + (threadIdx.x >> 6);
    if (node >= n) return;
    int lane = threadIdx.x & 63;
    float2 p = up_bf2(t2u[(size_t)node * 64 + lane]);  // self (t2' = dinv*t2)
    float a0 = p.x, a1 = p.y;
    int e0 = row_ptr[node], e1 = row_ptr[node + 1];
    int e = e0;
    for (; e + 8 <= e1; e += 8) {
        int si[8];
        uint ri[8];
#pragma unroll
        for (int j = 0; j < 8; ++j) si[j] = csr[e + j];
#pragma unroll
        for (int j = 0; j < 8; ++j) ri[j] = t2u[(size_t)si[j] * 64 + lane];
#pragma unroll
        for (int j = 0; j < 8; ++j) {
            float2 q = up_bf2(ri[j]);
            a0 += q.x;
            a1 += q.y;
        }
    }
    for (; e + 2 <= e1; e += 2) {
        int s0 = csr[e], s1 = csr[e + 1];
        uint r0 = t2u[(size_t)s0 * 64 + lane];
        uint r1 = t2u[(size_t)s1 * 64 + lane];
        float2 q0 = up_bf2(r0), q1 = up_bf2(r1);
        a0 += q0.x + q1.x;
        a1 += q0.y + q1.y;
    }
    if (e < e1) {
        float2 q0 = up_bf2(t2u[(size_t)csr[e] * 64 + lane]);
        a0 += q0.x;
        a1 += q0.y;
    }
    float di = dinv[node];
    float2 bb = *reinterpret_cast<const float2*>(b2 + 2 * lane);
    float h0 = fmaxf(di * a0 + bb.x, 0.f);
    float h1v = fmaxf(di * a1 + bb.y, 0.f);
    float4 wv = *reinterpret_cast<const float4*>(W3 + 4 * lane);
    float c0 = h0 * wv.x + h1v * wv.z;
    float c1 = h0 * wv.y + h1v * wv.w;
#pragma unroll
    for (int off = 32; off; off >>= 1) {
        c0 += __shfl_xor(c0, off);
        c1 += __shfl_xor(c1, off);
    }
    if (lane == 0) t3[node] = make_float2(di * c0, di * c1);  // prescaled
}

// ---------------- Layer 3 aggregate + log_softmax ----------------

__global__ void k_agg3(const float2* __restrict__ t3, const float* __restrict__ dinv,
                       const int* __restrict__ row_ptr, const int* __restrict__ csr,
                       const float* __restrict__ b3, float2* __restrict__ outv, int n) {
    int node = blockIdx.x * blockDim.x + threadIdx.x;
    if (node >= n) return;
    float2 s = t3[node];  // self (t3' = dinv*t3)
    float a0 = s.x, a1 = s.y;
    int e0 = row_ptr[node], e1 = row_ptr[node + 1];
    int e = e0;
    for (; e + 4 <= e1; e += 4) {
        int s0 = csr[e], s1 = csr[e + 1], s2 = csr[e + 2], s3 = csr[e + 3];
        float2 q0 = t3[s0], q1 = t3[s1], q2 = t3[s2], q3 = t3[s3];
        a0 += q0.x + q1.x + q2.x + q3.x;
        a1 += q0.y + q1.y + q2.y + q3.y;
    }
    for (; e < e1; ++e) {
        float2 q0 = t3[csr[e]];
        a0 += q0.x;
        a1 += q0.y;
    }
    float di = dinv[node];
    float z0 = di * a0 + b3[0];
    float z1 = di * a1 + b3[1];
    float m = fmaxf(z0, z1);
    float lse = m + logf(expf(z0 - m) + expf(z1 - m));
    outv[node] = make_float2(z0 - lse, z1 - lse);
}

// ---------------- launch ----------------

extern "C" void kernel_launch(void* const* d_in, const int* in_sizes, int n_in,
                              void* d_out, int out_size, void* d_ws, size_t ws_size,
                              hipStream_t stream) {
    const float* x  = (const float*)d_in[0];
    const float* W1 = (const float*)d_in[1];
    const float* b1 = (const float*)d_in[2];
    const float* W2 = (const float*)d_in[3];
    const float* b2 = (const float*)d_in[4];
    const float* W3 = (const float*)d_in[5];
    const float* b3 = (const float*)d_in[6];
    const int* edges = (const int*)d_in[7];

    int n = in_sizes[0] / 9;
    int E = in_sizes[7] / 2;
    const int* src = edges;
    const int* dst = edges + E;

    char* p = (char*)d_ws;
    auto alloc = [&](size_t bytes) {
        char* q = p;
        p += (bytes + 511) & ~(size_t)511;
        return q;
    };
    int npad = (n + 63) & ~63;
    int*   deg     = (int*)alloc((size_t)n * 4);
    float* dinv    = (float*)alloc((size_t)n * 4);
    int*   row_ptr = (int*)alloc((size_t)(n + 1) * 4);
    int*   csr     = (int*)alloc((size_t)E * 4);
    int*   histBlk = (int*)alloc((size_t)256 * NBLK * 4);
    int*   baseBlk = (int*)alloc((size_t)256 * NBLK * 4);
    uint2* binned  = (uint2*)alloc((size_t)E * 8);
    float* xs      = (float*)alloc((size_t)n * 9 * 4);
    float* aggx    = (float*)alloc((size_t)n * 9 * 4);
    __hip_bfloat16* h1 = (__hip_bfloat16*)alloc((size_t)npad * 512 * 2);
    __hip_bfloat16* t2 = (__hip_bfloat16*)alloc((size_t)n * 128 * 2);
    float2* t3 = (float2*)alloc((size_t)n * 8);

    const int B = 256;
    int shift = 8;
    while ((((n - 1) >> shift) + 1) > 256) shift++;
    int nbuck = ((n - 1) >> shift) + 1;
    int chunk = (E + NBLK - 1) / NBLK;

    hipMemsetAsync(deg, 0, (size_t)n * 4, stream);
    k_deghist<<<NBLK, B, 0, stream>>>(dst, E, chunk, shift, nbuck, deg, histBlk);
    k_scan<<<1, 1024, 0, stream>>>(deg, row_ptr, n);
    k_dinvxs<<<(n + B - 1) / B, B, 0, stream>>>(deg, x, dinv, xs, n);
    k_bscan<<<nbuck, B, 0, stream>>>(histBlk, row_ptr, shift, baseBlk);
    k_scatterbin<<<NBLK, B, 0, stream>>>(src, dst, E, chunk, shift, nbuck, baseBlk, binned);
    k_csrbuild<<<nbuck, B, 0, stream>>>(binned, row_ptr, csr, shift, n);

    k_agg1<<<(n + 15) / 16, B, 0, stream>>>(xs, dinv, row_ptr, csr, aggx, n);
    k_l1mm<<<((size_t)n * 64 + B - 1) / B, B, 0, stream>>>(aggx, W1, b1, h1, n);

    int nchunk = (n + 63) / 64;
    dim3 g2((nchunk + 3) / 4, 2);
    k_l2mm<<<g2, 256, 0, stream>>>(h1, W2, dinv, t2, n, nchunk);
    k_agg2<<<(n + 3) / 4, 256, 0, stream>>>((const uint*)t2, dinv, row_ptr, csr, b2, W3, t3, n);

    k_agg3<<<(n + B - 1) / B, B, 0, stream>>>(t3, dinv, row_ptr, csr, b3, (float2*)d_out, n);
}

// Round 10
// 263.739 us; speedup vs baseline: 1.2562x; 1.2562x over previous
//
#include <hip/hip_runtime.h>
#include <hip/hip_bf16.h>

typedef __attribute__((ext_vector_type(8))) short short8;
typedef __attribute__((ext_vector_type(4))) float float4v;
typedef unsigned int uint;

#define NBLK 192  // blocks for deghist/scatterbin passes

static __device__ __forceinline__ float2 up_bf2(uint v) {
    float2 r;
    r.x = __uint_as_float(v << 16);
    r.y = __uint_as_float(v & 0xffff0000u);
    return r;
}
static __device__ __forceinline__ short f2bf_bits(float x) {
    union { __hip_bfloat16 h; short s; } u;
    u.h = __float2bfloat16(x);
    return u.s;
}

// ---------------- degree + per-block bucket histogram (fused) ----------------

__global__ __launch_bounds__(256) void k_deghist(const int* __restrict__ dst, int E, int chunk,
        int shift, int nbuck, int* __restrict__ deg, int* __restrict__ histBlk) {
    __shared__ int h[256];
    h[threadIdx.x] = 0;
    __syncthreads();
    int blk = blockIdx.x;
    int e0 = blk * chunk, e1 = min(E, e0 + chunk);
    for (int e = e0 + threadIdx.x; e < e1; e += 256) {
        int d = dst[e];
        atomicAdd(&deg[d], 1);
        atomicAdd(&h[d >> shift], 1);
    }
    __syncthreads();
    if (threadIdx.x < nbuck) histBlk[threadIdx.x * NBLK + blk] = h[threadIdx.x];
}

// ---------------- row_ptr scan (3-kernel coalesced chain) ----------------
// NOTE: single-block serial-segment scan was 76.8us (uncoalesced, 1 CU);
// this chain is ~9us.

__global__ void k_scan1(const int* __restrict__ deg, int* __restrict__ incl,
                        int* __restrict__ bsum, int n) {
    __shared__ int s[1024];
    int i = blockIdx.x * 1024 + threadIdx.x;
    int v = (i < n) ? deg[i] : 0;
    s[threadIdx.x] = v;
    __syncthreads();
    for (int off = 1; off < 1024; off <<= 1) {
        int t = (threadIdx.x >= off) ? s[threadIdx.x - off] : 0;
        __syncthreads();
        s[threadIdx.x] += t;
        __syncthreads();
    }
    if (i < n) incl[i] = s[threadIdx.x];
    if (threadIdx.x == 1023) bsum[blockIdx.x] = s[1023];
}

__global__ void k_scan2(int* __restrict__ bsum, int nb) {
    __shared__ int s[1024];
    int tid = threadIdx.x;
    int v = (tid < nb) ? bsum[tid] : 0;
    int orig = v;
    s[tid] = v;
    __syncthreads();
    for (int off = 1; off < 1024; off <<= 1) {
        int t = (tid >= off) ? s[tid - off] : 0;
        __syncthreads();
        s[tid] += t;
        __syncthreads();
    }
    if (tid < nb) bsum[tid] = s[tid] - orig;  // exclusive block offsets
}

__global__ void k_scan3(const int* __restrict__ incl, const int* __restrict__ deg,
                        const int* __restrict__ bofs, int* __restrict__ row_ptr, int n) {
    int i = blockIdx.x * blockDim.x + threadIdx.x;
    if (i >= n) return;
    row_ptr[i] = bofs[i >> 10] + incl[i] - deg[i];
    if (i == n - 1) row_ptr[n] = bofs[i >> 10] + incl[i];
}

// ---------------- dinv + prescaled features (fused) ----------------

__global__ void k_dinvxs(const int* __restrict__ deg, const float* __restrict__ x,
                         float* __restrict__ dinv, float* __restrict__ xs, int n) {
    int i = blockIdx.x * blockDim.x + threadIdx.x;
    if (i >= n) return;
    float di = rsqrtf((float)(deg[i] + 1));  // +1 self-loop
    dinv[i] = di;
    const float* xp = x + (size_t)i * 9;
    float* xo = xs + (size_t)i * 9;
#pragma unroll
    for (int f = 0; f < 9; ++f) xo[f] = di * xp[f];
}

// ---------------- CSR build: 2-level counting sort ----------------

__global__ __launch_bounds__(256) void k_bscan(const int* __restrict__ histBlk,
                                               const int* __restrict__ row_ptr,
                                               int shift, int* __restrict__ baseBlk) {
    __shared__ int s[256];
    int b = blockIdx.x, t = threadIdx.x;
    int v = (t < NBLK) ? histBlk[b * NBLK + t] : 0;
    s[t] = v;
    __syncthreads();
    for (int off = 1; off < 256; off <<= 1) {
        int u = (t >= off) ? s[t - off] : 0;
        __syncthreads();
        s[t] += u;
        __syncthreads();
    }
    if (t < NBLK) baseBlk[b * NBLK + t] = row_ptr[b << shift] + s[t] - v;
}

__global__ __launch_bounds__(256) void k_scatterbin(const int* __restrict__ src,
        const int* __restrict__ dst, int E, int chunk, int shift, int nbuck,
        const int* __restrict__ baseBlk, uint2* __restrict__ binned) {
    __shared__ int cur[256];
    int blk = blockIdx.x;
    if (threadIdx.x < nbuck) cur[threadIdx.x] = baseBlk[threadIdx.x * NBLK + blk];
    __syncthreads();
    int e0 = blk * chunk, e1 = min(E, e0 + chunk);
    for (int e = e0 + threadIdx.x; e < e1; e += 256) {
        int d = dst[e];
        int pos = atomicAdd(&cur[d >> shift], 1);
        binned[pos] = make_uint2((uint)src[e], (uint)d);
    }
}

// per-bucket exact scatter; cursors in LDS (no global atomics)
__global__ __launch_bounds__(256) void k_csrbuild(const uint2* __restrict__ binned,
        const int* __restrict__ row_ptr, int* __restrict__ csr, int shift, int n) {
    __shared__ int lcur[512];
    int b = blockIdx.x;
    int node0 = b << shift;
    int nodeEnd = (b + 1) << shift;
    if (nodeEnd > n) nodeEnd = n;
    int cnt = nodeEnd - node0;
    for (int i = threadIdx.x; i < cnt; i += 256) lcur[i] = row_ptr[node0 + i];
    __syncthreads();
    int lo = row_ptr[node0], hi = row_ptr[nodeEnd];
    for (int e = lo + threadIdx.x; e < hi; e += 256) {
        uint2 p = binned[e];
        int pos = atomicAdd(&lcur[(int)p.y - node0], 1);
        csr[pos] = (int)p.x;
    }
}

// ---------------- Layer 1 aggregate: aggx = dinv .* (sum_s xs[s] + xs[node]) ----------------

__global__ __launch_bounds__(256) void k_agg1(const float* __restrict__ xs,
                       const float* __restrict__ dinv,
                       const int* __restrict__ row_ptr, const int* __restrict__ csr,
                       float* __restrict__ aggx, int n) {
    int node = blockIdx.x * 16 + (threadIdx.x >> 4);
    if (node >= n) return;
    int f = threadIdx.x & 15;
    bool act = f < 9;
    float acc = act ? xs[node * 9 + f] : 0.f;  // self-loop (xs = dinv*x)
    int e0 = row_ptr[node], e1 = row_ptr[node + 1];
    int e = e0;
    for (; e + 2 <= e1; e += 2) {
        int sA = csr[e], sB = csr[e + 1];
        float xa = act ? xs[sA * 9 + f] : 0.f;
        float xb = act ? xs[sB * 9 + f] : 0.f;
        acc += xa + xb;
    }
    if (e < e1) {
        int sA = csr[e];
        acc += act ? xs[sA * 9 + f] : 0.f;
    }
    if (act) aggx[node * 9 + f] = dinv[node] * acc;
}

// ---------------- Layer 1 matmul: h1 = relu(aggx @ W1 + b1), bf16 ----------------

__global__ __launch_bounds__(256) void k_l1mm(const float* __restrict__ agg,
                       const float* __restrict__ W1,
                       const float* __restrict__ b1, __hip_bfloat16* __restrict__ h1, int n) {
    int t = blockIdx.x * blockDim.x + threadIdx.x;
    if (t >= n * 64) return;
    int node = t >> 6, j0 = (t & 63) << 3;
    const float* a = agg + node * 9;
    float av[9];
#pragma unroll
    for (int f = 0; f < 9; ++f) av[f] = a[f];
    float acc[8];
#pragma unroll
    for (int j = 0; j < 8; ++j) acc[j] = b1[j0 + j];
#pragma unroll
    for (int f = 0; f < 9; ++f)
#pragma unroll
        for (int j = 0; j < 8; ++j) acc[j] += av[f] * W1[f * 512 + j0 + j];
    short8 o;
#pragma unroll
    for (int j = 0; j < 8; ++j) o[j] = f2bf_bits(fmaxf(acc[j], 0.f));
    *reinterpret_cast<short8*>(h1 + (size_t)node * 512 + j0) = o;
}

// ---------------- Layer 2 GEMM: t2' = dinv .* (h1 @ W2), bf16 MFMA ----------------

__global__ __launch_bounds__(256, 2) void k_l2mm(const __hip_bfloat16* __restrict__ h1,
                       const float* __restrict__ W2, const float* __restrict__ dinv,
                       __hip_bfloat16* __restrict__ t2, int n, int nchunk) {
    __shared__ short bsh[64 * 64 * 8];  // 64 KB: [kb 0..63][c 0..63][j 0..7]
    int t = threadIdx.x;
    int colbase = blockIdx.y << 6;

    for (int idx = t; idx < 64 * 64; idx += 256) {
        int kb = idx >> 6, c = idx & 63;
        const float* wp = W2 + (size_t)(kb * 8) * 128 + colbase + c;
        short8 o;
#pragma unroll
        for (int j = 0; j < 8; ++j) o[j] = f2bf_bits(wp[j * 128]);
        *reinterpret_cast<short8*>(bsh + (size_t)idx * 8) = o;
    }
    __syncthreads();

    int wid = t >> 6, lane = t & 63;
    int chunk = blockIdx.x * 4 + wid;
    if (chunk >= nchunk) return;
    int r = lane & 15, quad = lane >> 4;
    int m0 = chunk << 6;

    float4v acc[4][4];
#pragma unroll
    for (int mt = 0; mt < 4; ++mt)
#pragma unroll
        for (int cg = 0; cg < 4; ++cg) acc[mt][cg] = (float4v){0, 0, 0, 0};

#pragma unroll
    for (int kt = 0; kt < 16; ++kt) {
        short8 a[4], b[4];
#pragma unroll
        for (int mt = 0; mt < 4; ++mt)
            a[mt] = *reinterpret_cast<const short8*>(
                h1 + (size_t)(m0 + mt * 16 + r) * 512 + kt * 32 + quad * 8);
#pragma unroll
        for (int cg = 0; cg < 4; ++cg)
            b[cg] = *reinterpret_cast<const short8*>(
                bsh + (size_t)(((kt * 4 + quad) * 64) + cg * 16 + r) * 8);
#pragma unroll
        for (int mt = 0; mt < 4; ++mt)
#pragma unroll
            for (int cg = 0; cg < 4; ++cg)
                acc[mt][cg] = __builtin_amdgcn_mfma_f32_16x16x32_bf16(a[mt], b[cg], acc[mt][cg], 0, 0, 0);
    }

#pragma unroll
    for (int mt = 0; mt < 4; ++mt)
#pragma unroll
        for (int i = 0; i < 4; ++i) {
            int node = m0 + mt * 16 + quad * 4 + i;
            if (node < n) {
                float di = dinv[node];
                __hip_bfloat16* op = t2 + (size_t)node * 128 + colbase + r;
#pragma unroll
                for (int cg = 0; cg < 4; ++cg)
                    op[cg * 16] = __float2bfloat16(di * acc[mt][cg][i]);
            }
        }
}

// ---------------- Layer 2 aggregate + fused layer-3 matmul ----------------
// wave per node; 8 independent 256B row reads in flight per iteration.

__global__ __launch_bounds__(256) void k_agg2(const uint* __restrict__ t2u,
                       const float* __restrict__ dinv,
                       const int* __restrict__ row_ptr, const int* __restrict__ csr,
                       const float* __restrict__ b2, const float* __restrict__ W3,
                       float2* __restrict__ t3, int n) {
    int node = blockIdx.x * 4 + (threadIdx.x >> 6);
    if (node >= n) return;
    int lane = threadIdx.x & 63;
    float2 p = up_bf2(t2u[(size_t)node * 64 + lane]);  // self (t2' = dinv*t2)
    float a0 = p.x, a1 = p.y;
    int e0 = row_ptr[node], e1 = row_ptr[node + 1];
    int e = e0;
    for (; e + 8 <= e1; e += 8) {
        int si[8];
        uint ri[8];
#pragma unroll
        for (int j = 0; j < 8; ++j) si[j] = csr[e + j];
#pragma unroll
        for (int j = 0; j < 8; ++j) ri[j] = t2u[(size_t)si[j] * 64 + lane];
#pragma unroll
        for (int j = 0; j < 8; ++j) {
            float2 q = up_bf2(ri[j]);
            a0 += q.x;
            a1 += q.y;
        }
    }
    for (; e + 2 <= e1; e += 2) {
        int s0 = csr[e], s1 = csr[e + 1];
        uint r0 = t2u[(size_t)s0 * 64 + lane];
        uint r1 = t2u[(size_t)s1 * 64 + lane];
        float2 q0 = up_bf2(r0), q1 = up_bf2(r1);
        a0 += q0.x + q1.x;
        a1 += q0.y + q1.y;
    }
    if (e < e1) {
        float2 q0 = up_bf2(t2u[(size_t)csr[e] * 64 + lane]);
        a0 += q0.x;
        a1 += q0.y;
    }
    float di = dinv[node];
    float2 bb = *reinterpret_cast<const float2*>(b2 + 2 * lane);
    float h0 = fmaxf(di * a0 + bb.x, 0.f);
    float h1v = fmaxf(di * a1 + bb.y, 0.f);
    float4 wv = *reinterpret_cast<const float4*>(W3 + 4 * lane);
    float c0 = h0 * wv.x + h1v * wv.z;
    float c1 = h0 * wv.y + h1v * wv.w;
#pragma unroll
    for (int off = 32; off; off >>= 1) {
        c0 += __shfl_xor(c0, off);
        c1 += __shfl_xor(c1, off);
    }
    if (lane == 0) t3[node] = make_float2(di * c0, di * c1);  // prescaled
}

// ---------------- Layer 3 aggregate + log_softmax ----------------

__global__ void k_agg3(const float2* __restrict__ t3, const float* __restrict__ dinv,
                       const int* __restrict__ row_ptr, const int* __restrict__ csr,
                       const float* __restrict__ b3, float2* __restrict__ outv, int n) {
    int node = blockIdx.x * blockDim.x + threadIdx.x;
    if (node >= n) return;
    float2 s = t3[node];  // self (t3' = dinv*t3)
    float a0 = s.x, a1 = s.y;
    int e0 = row_ptr[node], e1 = row_ptr[node + 1];
    int e = e0;
    for (; e + 4 <= e1; e += 4) {
        int s0 = csr[e], s1 = csr[e + 1], s2 = csr[e + 2], s3 = csr[e + 3];
        float2 q0 = t3[s0], q1 = t3[s1], q2 = t3[s2], q3 = t3[s3];
        a0 += q0.x + q1.x + q2.x + q3.x;
        a1 += q0.y + q1.y + q2.y + q3.y;
    }
    for (; e < e1; ++e) {
        float2 q0 = t3[csr[e]];
        a0 += q0.x;
        a1 += q0.y;
    }
    float di = dinv[node];
    float z0 = di * a0 + b3[0];
    float z1 = di * a1 + b3[1];
    float m = fmaxf(z0, z1);
    float lse = m + logf(expf(z0 - m) + expf(z1 - m));
    outv[node] = make_float2(z0 - lse, z1 - lse);
}

// ---------------- launch ----------------

extern "C" void kernel_launch(void* const* d_in, const int* in_sizes, int n_in,
                              void* d_out, int out_size, void* d_ws, size_t ws_size,
                              hipStream_t stream) {
    const float* x  = (const float*)d_in[0];
    const float* W1 = (const float*)d_in[1];
    const float* b1 = (const float*)d_in[2];
    const float* W2 = (const float*)d_in[3];
    const float* b2 = (const float*)d_in[4];
    const float* W3 = (const float*)d_in[5];
    const float* b3 = (const float*)d_in[6];
    const int* edges = (const int*)d_in[7];

    int n = in_sizes[0] / 9;
    int E = in_sizes[7] / 2;
    const int* src = edges;
    const int* dst = edges + E;

    char* p = (char*)d_ws;
    auto alloc = [&](size_t bytes) {
        char* q = p;
        p += (bytes + 511) & ~(size_t)511;
        return q;
    };
    int npad = (n + 63) & ~63;
    int*   deg     = (int*)alloc((size_t)n * 4);
    float* dinv    = (float*)alloc((size_t)n * 4);
    int*   incl    = (int*)alloc((size_t)n * 4);
    int*   bsum    = (int*)alloc(4096);
    int*   row_ptr = (int*)alloc((size_t)(n + 1) * 4);
    int*   csr     = (int*)alloc((size_t)E * 4);
    int*   histBlk = (int*)alloc((size_t)256 * NBLK * 4);
    int*   baseBlk = (int*)alloc((size_t)256 * NBLK * 4);
    uint2* binned  = (uint2*)alloc((size_t)E * 8);
    float* xs      = (float*)alloc((size_t)n * 9 * 4);
    float* aggx    = (float*)alloc((size_t)n * 9 * 4);
    __hip_bfloat16* h1 = (__hip_bfloat16*)alloc((size_t)npad * 512 * 2);
    __hip_bfloat16* t2 = (__hip_bfloat16*)alloc((size_t)n * 128 * 2);
    float2* t3 = (float2*)alloc((size_t)n * 8);

    const int B = 256;
    int shift = 8;
    while ((((n - 1) >> shift) + 1) > 256) shift++;
    int nbuck = ((n - 1) >> shift) + 1;
    int chunk = (E + NBLK - 1) / NBLK;

    hipMemsetAsync(deg, 0, (size_t)n * 4, stream);
    k_deghist<<<NBLK, B, 0, stream>>>(dst, E, chunk, shift, nbuck, deg, histBlk);
    int nb = (n + 1023) / 1024;
    k_scan1<<<nb, 1024, 0, stream>>>(deg, incl, bsum, n);
    k_scan2<<<1, 1024, 0, stream>>>(bsum, nb);
    k_scan3<<<(n + B - 1) / B, B, 0, stream>>>(incl, deg, bsum, row_ptr, n);
    k_dinvxs<<<(n + B - 1) / B, B, 0, stream>>>(deg, x, dinv, xs, n);
    k_bscan<<<nbuck, B, 0, stream>>>(histBlk, row_ptr, shift, baseBlk);
    k_scatterbin<<<NBLK, B, 0, stream>>>(src, dst, E, chunk, shift, nbuck, baseBlk, binned);
    k_csrbuild<<<nbuck, B, 0, stream>>>(binned, row_ptr, csr, shift, n);

    k_agg1<<<(n + 15) / 16, B, 0, stream>>>(xs, dinv, row_ptr, csr, aggx, n);
    k_l1mm<<<((size_t)n * 64 + B - 1) / B, B, 0, stream>>>(aggx, W1, b1, h1, n);

    int nchunk = (n + 63) / 64;
    dim3 g2((nchunk + 3) / 4, 2);
    k_l2mm<<<g2, 256, 0, stream>>>(h1, W2, dinv, t2, n, nchunk);
    k_agg2<<<(n + 3) / 4, 256, 0, stream>>>((const uint*)t2, dinv, row_ptr, csr, b2, W3, t3, n);

    k_agg3<<<(n + B - 1) / B, B, 0, stream>>>(t3, dinv, row_ptr, csr, b3, (float2*)d_out, n);
}

// Round 11
// 230.053 us; speedup vs baseline: 1.4401x; 1.1464x over previous
//
#include <hip/hip_runtime.h>
#include <hip/hip_bf16.h>

typedef __attribute__((ext_vector_type(8))) short short8;
typedef __attribute__((ext_vector_type(4))) float float4v;
typedef unsigned int uint;

#define NBLK 192  // blocks for hist/scatterbin passes

static __device__ __forceinline__ float2 up_bf2(uint v) {
    float2 r;
    r.x = __uint_as_float(v << 16);
    r.y = __uint_as_float(v & 0xffff0000u);
    return r;
}
static __device__ __forceinline__ short f2bf_bits(float x) {
    union { __hip_bfloat16 h; short s; } u;
    u.h = __float2bfloat16(x);
    return u.s;
}

// ---------------- per-(bucket,block) histogram, LDS only ----------------
// (global per-node deg atomics eliminated; per-node counts recomputed in k_csrbuild)

__global__ __launch_bounds__(256) void k_hist(const int* __restrict__ dst, int E, int chunk,
        int shift, int nbuck, int* __restrict__ histBlk) {
    __shared__ int h[256];
    h[threadIdx.x] = 0;
    __syncthreads();
    int blk = blockIdx.x;
    int e0 = blk * chunk, e1 = min(E, e0 + chunk);
    for (int e = e0 + threadIdx.x; e < e1; e += 256)
        atomicAdd(&h[dst[e] >> shift], 1);
    __syncthreads();
    if (threadIdx.x < nbuck) histBlk[threadIdx.x * NBLK + blk] = h[threadIdx.x];
}

// ---------------- bucket totals ----------------

__global__ __launch_bounds__(256) void k_btot(const int* __restrict__ histBlk,
                                              int* __restrict__ btot) {
    __shared__ int s[256];
    int b = blockIdx.x, t = threadIdx.x;
    s[t] = (t < NBLK) ? histBlk[b * NBLK + t] : 0;
    __syncthreads();
    for (int off = 128; off; off >>= 1) {
        if (t < off) s[t] += s[t + off];
        __syncthreads();
    }
    if (t == 0) btot[b] = s[0];
}

// ---------------- per-(bucket,block) bases + bucket bases ----------------

__global__ __launch_bounds__(256) void k_bscan(const int* __restrict__ histBlk,
        const int* __restrict__ btot, int nbuck,
        int* __restrict__ baseBlk, int* __restrict__ bucketBase) {
    __shared__ int s[256], sb[256];
    int b = blockIdx.x, t = threadIdx.x;
    int v = (t < NBLK) ? histBlk[b * NBLK + t] : 0;
    s[t] = v;
    sb[t] = (t < nbuck) ? btot[t] : 0;
    __syncthreads();
    for (int off = 1; off < 256; off <<= 1) {
        int u = (t >= off) ? s[t - off] : 0;
        int u2 = (t >= off) ? sb[t - off] : 0;
        __syncthreads();
        s[t] += u;
        sb[t] += u2;
        __syncthreads();
    }
    int base = (b > 0) ? sb[b - 1] : 0;  // exclusive prefix of bucket totals
    if (t < NBLK) baseBlk[b * NBLK + t] = base + s[t] - v;
    if (t == 0) bucketBase[b] = base;
}

// ---------------- scatter into per-(bucket,block) slices, packed payload ----------------
// binned word = src (24b) | dst_local (8b).  Requires n < 2^24 and shift == 8.

__global__ __launch_bounds__(256) void k_scatterbin(const int* __restrict__ src,
        const int* __restrict__ dst, int E, int chunk, int shift, int nbuck,
        const int* __restrict__ baseBlk, uint* __restrict__ binned) {
    __shared__ int cur[256];
    int blk = blockIdx.x;
    if (threadIdx.x < nbuck) cur[threadIdx.x] = baseBlk[threadIdx.x * NBLK + blk];
    __syncthreads();
    int e0 = blk * chunk, e1 = min(E, e0 + chunk);
    int mask = (1 << shift) - 1;
    for (int e = e0 + threadIdx.x; e < e1; e += 256) {
        int d = dst[e];
        int pos = atomicAdd(&cur[d >> shift], 1);
        binned[pos] = (uint)src[e] | ((uint)(d & mask) << 24);
    }
}

// ---------------- per-bucket: counts -> row_ptr/dinv/xs, then exact csr scatter ----------------

__global__ __launch_bounds__(256) void k_csrbuild(const uint* __restrict__ binned,
        const int* __restrict__ bucketBase, const float* __restrict__ x,
        int E, int shift, int n, int nbuck,
        int* __restrict__ row_ptr, float* __restrict__ dinv, float* __restrict__ xs,
        int* __restrict__ csr) {
    __shared__ int cnt[256], lcur[256];
    int b = blockIdx.x, t = threadIdx.x;
    cnt[t] = 0;
    __syncthreads();
    int lo = bucketBase[b];
    int hi = (b + 1 < nbuck) ? bucketBase[b + 1] : E;
    for (int e = lo + t; e < hi; e += 256)
        atomicAdd(&cnt[binned[e] >> 24], 1);
    __syncthreads();
    int c = cnt[t];
    lcur[t] = c;
    __syncthreads();
    for (int off = 1; off < 256; off <<= 1) {
        int u = (t >= off) ? lcur[t - off] : 0;
        __syncthreads();
        lcur[t] += u;
        __syncthreads();
    }
    int node0 = b << shift;
    int nodeEnd = min(n, (b + 1) << shift);
    int cntNodes = nodeEnd - node0;
    int myBase = lo + lcur[t] - c;  // exclusive prefix within bucket
    if (t < cntNodes) {
        row_ptr[node0 + t] = myBase;
        dinv[node0 + t] = rsqrtf((float)(c + 1));  // +1 self-loop
    }
    if (b == nbuck - 1 && t == 0) row_ptr[n] = E;
    // prescaled features xs = dinv * x for this bucket's nodes
    for (int j = t; j < cntNodes * 9; j += 256) {
        int nl = j / 9, f = j - nl * 9;
        float dnl = rsqrtf((float)(cnt[nl] + 1));
        xs[(size_t)(node0 + nl) * 9 + f] = dnl * x[(size_t)(node0 + nl) * 9 + f];
    }
    __syncthreads();
    lcur[t] = myBase;  // running cursors
    __syncthreads();
    for (int e = lo + t; e < hi; e += 256) {
        uint p = binned[e];
        int pos = atomicAdd(&lcur[p >> 24], 1);
        csr[pos] = (int)(p & 0xFFFFFF);
    }
}

// ---------------- Layer 1 aggregate: aggx = dinv .* (sum_s xs[s] + xs[node]) ----------------

__global__ __launch_bounds__(256) void k_agg1(const float* __restrict__ xs,
                       const float* __restrict__ dinv,
                       const int* __restrict__ row_ptr, const int* __restrict__ csr,
                       float* __restrict__ aggx, int n) {
    int node = blockIdx.x * 16 + (threadIdx.x >> 4);
    if (node >= n) return;
    int f = threadIdx.x & 15;
    bool act = f < 9;
    float acc = act ? xs[node * 9 + f] : 0.f;  // self-loop (xs = dinv*x)
    int e0 = row_ptr[node], e1 = row_ptr[node + 1];
    int e = e0;
    for (; e + 4 <= e1; e += 4) {
        int s0 = csr[e], s1 = csr[e + 1], s2 = csr[e + 2], s3 = csr[e + 3];
        float x0 = act ? xs[s0 * 9 + f] : 0.f;
        float x1 = act ? xs[s1 * 9 + f] : 0.f;
        float x2 = act ? xs[s2 * 9 + f] : 0.f;
        float x3 = act ? xs[s3 * 9 + f] : 0.f;
        acc += (x0 + x1) + (x2 + x3);
    }
    for (; e < e1; ++e) {
        int sA = csr[e];
        acc += act ? xs[sA * 9 + f] : 0.f;
    }
    if (act) aggx[node * 9 + f] = dinv[node] * acc;
}

// ---------------- Layer 1 matmul: h1 = relu(aggx @ W1 + b1), bf16 ----------------

__global__ __launch_bounds__(256) void k_l1mm(const float* __restrict__ agg,
                       const float* __restrict__ W1,
                       const float* __restrict__ b1, __hip_bfloat16* __restrict__ h1, int n) {
    int t = blockIdx.x * blockDim.x + threadIdx.x;
    if (t >= n * 64) return;
    int node = t >> 6, j0 = (t & 63) << 3;
    const float* a = agg + node * 9;
    float av[9];
#pragma unroll
    for (int f = 0; f < 9; ++f) av[f] = a[f];
    float acc[8];
#pragma unroll
    for (int j = 0; j < 8; ++j) acc[j] = b1[j0 + j];
#pragma unroll
    for (int f = 0; f < 9; ++f)
#pragma unroll
        for (int j = 0; j < 8; ++j) acc[j] += av[f] * W1[f * 512 + j0 + j];
    short8 o;
#pragma unroll
    for (int j = 0; j < 8; ++j) o[j] = f2bf_bits(fmaxf(acc[j], 0.f));
    *reinterpret_cast<short8*>(h1 + (size_t)node * 512 + j0) = o;
}

// ---------------- Layer 2 GEMM: t2' = dinv .* (h1 @ W2), bf16 MFMA ----------------

__global__ __launch_bounds__(256, 2) void k_l2mm(const __hip_bfloat16* __restrict__ h1,
                       const float* __restrict__ W2, const float* __restrict__ dinv,
                       __hip_bfloat16* __restrict__ t2, int n, int nchunk) {
    __shared__ short bsh[64 * 64 * 8];  // 64 KB: [kb 0..63][c 0..63][j 0..7]
    int t = threadIdx.x;
    int colbase = blockIdx.y << 6;

    for (int idx = t; idx < 64 * 64; idx += 256) {
        int kb = idx >> 6, c = idx & 63;
        const float* wp = W2 + (size_t)(kb * 8) * 128 + colbase + c;
        short8 o;
#pragma unroll
        for (int j = 0; j < 8; ++j) o[j] = f2bf_bits(wp[j * 128]);
        *reinterpret_cast<short8*>(bsh + (size_t)idx * 8) = o;
    }
    __syncthreads();

    int wid = t >> 6, lane = t & 63;
    int chunk = blockIdx.x * 4 + wid;
    if (chunk >= nchunk) return;
    int r = lane & 15, quad = lane >> 4;
    int m0 = chunk << 6;

    float4v acc[4][4];
#pragma unroll
    for (int mt = 0; mt < 4; ++mt)
#pragma unroll
        for (int cg = 0; cg < 4; ++cg) acc[mt][cg] = (float4v){0, 0, 0, 0};

#pragma unroll
    for (int kt = 0; kt < 16; ++kt) {
        short8 a[4], b[4];
#pragma unroll
        for (int mt = 0; mt < 4; ++mt)
            a[mt] = *reinterpret_cast<const short8*>(
                h1 + (size_t)(m0 + mt * 16 + r) * 512 + kt * 32 + quad * 8);
#pragma unroll
        for (int cg = 0; cg < 4; ++cg)
            b[cg] = *reinterpret_cast<const short8*>(
                bsh + (size_t)(((kt * 4 + quad) * 64) + cg * 16 + r) * 8);
#pragma unroll
        for (int mt = 0; mt < 4; ++mt)
#pragma unroll
            for (int cg = 0; cg < 4; ++cg)
                acc[mt][cg] = __builtin_amdgcn_mfma_f32_16x16x32_bf16(a[mt], b[cg], acc[mt][cg], 0, 0, 0);
    }

#pragma unroll
    for (int mt = 0; mt < 4; ++mt)
#pragma unroll
        for (int i = 0; i < 4; ++i) {
            int node = m0 + mt * 16 + quad * 4 + i;
            if (node < n) {
                float di = dinv[node];
                __hip_bfloat16* op = t2 + (size_t)node * 128 + colbase + r;
#pragma unroll
                for (int cg = 0; cg < 4; ++cg)
                    op[cg * 16] = __float2bfloat16(di * acc[mt][cg][i]);
            }
        }
}

// ---------------- Layer 2 aggregate + fused layer-3 matmul ----------------

__global__ __launch_bounds__(256) void k_agg2(const uint* __restrict__ t2u,
                       const float* __restrict__ dinv,
                       const int* __restrict__ row_ptr, const int* __restrict__ csr,
                       const float* __restrict__ b2, const float* __restrict__ W3,
                       float2* __restrict__ t3, int n) {
    int node = blockIdx.x * 4 + (threadIdx.x >> 6);
    if (node >= n) return;
    int lane = threadIdx.x & 63;
    float2 p = up_bf2(t2u[(size_t)node * 64 + lane]);  // self (t2' = dinv*t2)
    float a0 = p.x, a1 = p.y;
    int e0 = row_ptr[node], e1 = row_ptr[node + 1];
    int e = e0;
    for (; e + 8 <= e1; e += 8) {
        int si[8];
        uint ri[8];
#pragma unroll
        for (int j = 0; j < 8; ++j) si[j] = csr[e + j];
#pragma unroll
        for (int j = 0; j < 8; ++j) ri[j] = t2u[(size_t)si[j] * 64 + lane];
#pragma unroll
        for (int j = 0; j < 8; ++j) {
            float2 q = up_bf2(ri[j]);
            a0 += q.x;
            a1 += q.y;
        }
    }
    for (; e + 2 <= e1; e += 2) {
        int s0 = csr[e], s1 = csr[e + 1];
        uint r0 = t2u[(size_t)s0 * 64 + lane];
        uint r1 = t2u[(size_t)s1 * 64 + lane];
        float2 q0 = up_bf2(r0), q1 = up_bf2(r1);
        a0 += q0.x + q1.x;
        a1 += q0.y + q1.y;
    }
    if (e < e1) {
        float2 q0 = up_bf2(t2u[(size_t)csr[e] * 64 + lane]);
        a0 += q0.x;
        a1 += q0.y;
    }
    float di = dinv[node];
    float2 bb = *reinterpret_cast<const float2*>(b2 + 2 * lane);
    float h0 = fmaxf(di * a0 + bb.x, 0.f);
    float h1v = fmaxf(di * a1 + bb.y, 0.f);
    float4 wv = *reinterpret_cast<const float4*>(W3 + 4 * lane);
    float c0 = h0 * wv.x + h1v * wv.z;
    float c1 = h0 * wv.y + h1v * wv.w;
#pragma unroll
    for (int off = 32; off; off >>= 1) {
        c0 += __shfl_xor(c0, off);
        c1 += __shfl_xor(c1, off);
    }
    if (lane == 0) t3[node] = make_float2(di * c0, di * c1);  // prescaled
}

// ---------------- Layer 3 aggregate + log_softmax ----------------

__global__ void k_agg3(const float2* __restrict__ t3, const float* __restrict__ dinv,
                       const int* __restrict__ row_ptr, const int* __restrict__ csr,
                       const float* __restrict__ b3, float2* __restrict__ outv, int n) {
    int node = blockIdx.x * blockDim.x + threadIdx.x;
    if (node >= n) return;
    float2 s = t3[node];  // self (t3' = dinv*t3)
    float a0 = s.x, a1 = s.y;
    int e0 = row_ptr[node], e1 = row_ptr[node + 1];
    int e = e0;
    for (; e + 4 <= e1; e += 4) {
        int s0 = csr[e], s1 = csr[e + 1], s2 = csr[e + 2], s3 = csr[e + 3];
        float2 q0 = t3[s0], q1 = t3[s1], q2 = t3[s2], q3 = t3[s3];
        a0 += q0.x + q1.x + q2.x + q3.x;
        a1 += q0.y + q1.y + q2.y + q3.y;
    }
    for (; e < e1; ++e) {
        float2 q0 = t3[csr[e]];
        a0 += q0.x;
        a1 += q0.y;
    }
    float di = dinv[node];
    float z0 = di * a0 + b3[0];
    float z1 = di * a1 + b3[1];
    float m = fmaxf(z0, z1);
    float lse = m + logf(expf(z0 - m) + expf(z1 - m));
    outv[node] = make_float2(z0 - lse, z1 - lse);
}

// ---------------- launch ----------------

extern "C" void kernel_launch(void* const* d_in, const int* in_sizes, int n_in,
                              void* d_out, int out_size, void* d_ws, size_t ws_size,
                              hipStream_t stream) {
    const float* x  = (const float*)d_in[0];
    const float* W1 = (const float*)d_in[1];
    const float* b1 = (const float*)d_in[2];
    const float* W2 = (const float*)d_in[3];
    const float* b2 = (const float*)d_in[4];
    const float* W3 = (const float*)d_in[5];
    const float* b3 = (const float*)d_in[6];
    const int* edges = (const int*)d_in[7];

    int n = in_sizes[0] / 9;
    int E = in_sizes[7] / 2;
    const int* src = edges;
    const int* dst = edges + E;

    char* p = (char*)d_ws;
    auto alloc = [&](size_t bytes) {
        char* q = p;
        p += (bytes + 511) & ~(size_t)511;
        return q;
    };
    int npad = (n + 63) & ~63;
    float* dinv       = (float*)alloc((size_t)n * 4);
    int*   row_ptr    = (int*)alloc((size_t)(n + 1) * 4);
    int*   csr        = (int*)alloc((size_t)E * 4);
    int*   histBlk    = (int*)alloc((size_t)256 * NBLK * 4);
    int*   baseBlk    = (int*)alloc((size_t)256 * NBLK * 4);
    int*   btot       = (int*)alloc(256 * 4);
    int*   bucketBase = (int*)alloc(256 * 4);
    uint*  binned     = (uint*)alloc((size_t)E * 4);
    float* xs         = (float*)alloc((size_t)n * 9 * 4);
    float* aggx       = (float*)alloc((size_t)n * 9 * 4);
    __hip_bfloat16* h1 = (__hip_bfloat16*)alloc((size_t)npad * 512 * 2);
    __hip_bfloat16* t2 = (__hip_bfloat16*)alloc((size_t)n * 128 * 2);
    float2* t3 = (float2*)alloc((size_t)n * 8);

    const int B = 256;
    int shift = 8;  // packed binned requires shift==8 (dst_local 8b) and n < 2^24
    int nbuck = ((n - 1) >> shift) + 1;
    int chunk = (E + NBLK - 1) / NBLK;

    k_hist<<<NBLK, B, 0, stream>>>(dst, E, chunk, shift, nbuck, histBlk);
    k_btot<<<nbuck, B, 0, stream>>>(histBlk, btot);
    k_bscan<<<nbuck, B, 0, stream>>>(histBlk, btot, nbuck, baseBlk, bucketBase);
    k_scatterbin<<<NBLK, B, 0, stream>>>(src, dst, E, chunk, shift, nbuck, baseBlk, binned);
    k_csrbuild<<<nbuck, B, 0, stream>>>(binned, bucketBase, x, E, shift, n, nbuck,
                                        row_ptr, dinv, xs, csr);

    k_agg1<<<(n + 15) / 16, B, 0, stream>>>(xs, dinv, row_ptr, csr, aggx, n);
    k_l1mm<<<((size_t)n * 64 + B - 1) / B, B, 0, stream>>>(aggx, W1, b1, h1, n);

    int nchunk = (n + 63) / 64;
    dim3 g2((nchunk + 3) / 4, 2);
    k_l2mm<<<g2, 256, 0, stream>>>(h1, W2, dinv, t2, n, nchunk);
    k_agg2<<<(n + 3) / 4, 256, 0, stream>>>((const uint*)t2, dinv, row_ptr, csr, b2, W3, t3, n);

    k_agg3<<<(n + B - 1) / B, B, 0, stream>>>(t3, dinv, row_ptr, csr, b3, (float2*)d_out, n);
}

// Round 12
// 216.061 us; speedup vs baseline: 1.5334x; 1.0648x over previous
//
#include <hip/hip_runtime.h>
#include <hip/hip_bf16.h>

typedef __attribute__((ext_vector_type(8))) short short8;
typedef __attribute__((ext_vector_type(4))) float float4v;
typedef unsigned int uint;

#define NBLK 192  // blocks for hist/scatterbin passes

static __device__ __forceinline__ float2 up_bf2(uint v) {
    float2 r;
    r.x = __uint_as_float(v << 16);
    r.y = __uint_as_float(v & 0xffff0000u);
    return r;
}
static __device__ __forceinline__ short f2bf_bits(float x) {
    union { __hip_bfloat16 h; short s; } u;
    u.h = __float2bfloat16(x);
    return u.s;
}

// ---------------- per-(bucket,block) histogram, LDS only ----------------

__global__ __launch_bounds__(256) void k_hist(const int* __restrict__ dst, int E, int chunk,
        int shift, int nbuck, int* __restrict__ histBlk) {
    __shared__ int h[256];
    h[threadIdx.x] = 0;
    __syncthreads();
    int blk = blockIdx.x;
    int e0 = blk * chunk, e1 = min(E, e0 + chunk);
    for (int e = e0 + threadIdx.x; e < e1; e += 256)
        atomicAdd(&h[dst[e] >> shift], 1);
    __syncthreads();
    if (threadIdx.x < nbuck) histBlk[threadIdx.x * NBLK + blk] = h[threadIdx.x];
}

// ---------------- bucket totals ----------------

__global__ __launch_bounds__(256) void k_btot(const int* __restrict__ histBlk,
                                              int* __restrict__ btot) {
    __shared__ int s[256];
    int b = blockIdx.x, t = threadIdx.x;
    s[t] = (t < NBLK) ? histBlk[b * NBLK + t] : 0;
    __syncthreads();
    for (int off = 128; off; off >>= 1) {
        if (t < off) s[t] += s[t + off];
        __syncthreads();
    }
    if (t == 0) btot[b] = s[0];
}

// ---------------- per-(bucket,block) bases + bucket bases ----------------

__global__ __launch_bounds__(256) void k_bscan(const int* __restrict__ histBlk,
        const int* __restrict__ btot, int nbuck,
        int* __restrict__ baseBlk, int* __restrict__ bucketBase) {
    __shared__ int s[256], sb[256];
    int b = blockIdx.x, t = threadIdx.x;
    int v = (t < NBLK) ? histBlk[b * NBLK + t] : 0;
    s[t] = v;
    sb[t] = (t < nbuck) ? btot[t] : 0;
    __syncthreads();
    for (int off = 1; off < 256; off <<= 1) {
        int u = (t >= off) ? s[t - off] : 0;
        int u2 = (t >= off) ? sb[t - off] : 0;
        __syncthreads();
        s[t] += u;
        sb[t] += u2;
        __syncthreads();
    }
    int base = (b > 0) ? sb[b - 1] : 0;  // exclusive prefix of bucket totals
    if (t < NBLK) baseBlk[b * NBLK + t] = base + s[t] - v;
    if (t == 0) bucketBase[b] = base;
}

// ---------------- scatter into per-(bucket,block) slices, packed payload ----------------
// binned word = src (24b) | dst_local (8b).  Requires n < 2^24 and shift == 8.

__global__ __launch_bounds__(256) void k_scatterbin(const int* __restrict__ src,
        const int* __restrict__ dst, int E, int chunk, int shift, int nbuck,
        const int* __restrict__ baseBlk, uint* __restrict__ binned) {
    __shared__ int cur[256];
    int blk = blockIdx.x;
    if (threadIdx.x < nbuck) cur[threadIdx.x] = baseBlk[threadIdx.x * NBLK + blk];
    __syncthreads();
    int e0 = blk * chunk, e1 = min(E, e0 + chunk);
    int mask = (1 << shift) - 1;
    for (int e = e0 + threadIdx.x; e < e1; e += 256) {
        int d = dst[e];
        int pos = atomicAdd(&cur[d >> shift], 1);
        binned[pos] = (uint)src[e] | ((uint)(d & mask) << 24);
    }
}

// ---------------- per-bucket: counts -> row_ptr/dinv/xs, then exact csr scatter ----------------

__global__ __launch_bounds__(256) void k_csrbuild(const uint* __restrict__ binned,
        const int* __restrict__ bucketBase, const float* __restrict__ x,
        int E, int shift, int n, int nbuck,
        int* __restrict__ row_ptr, float* __restrict__ dinv, float* __restrict__ xs,
        int* __restrict__ csr) {
    __shared__ int cnt[256], lcur[256];
    int b = blockIdx.x, t = threadIdx.x;
    cnt[t] = 0;
    __syncthreads();
    int lo = bucketBase[b];
    int hi = (b + 1 < nbuck) ? bucketBase[b + 1] : E;
    for (int e = lo + t; e < hi; e += 256)
        atomicAdd(&cnt[binned[e] >> 24], 1);
    __syncthreads();
    int c = cnt[t];
    lcur[t] = c;
    __syncthreads();
    for (int off = 1; off < 256; off <<= 1) {
        int u = (t >= off) ? lcur[t - off] : 0;
        __syncthreads();
        lcur[t] += u;
        __syncthreads();
    }
    int node0 = b << shift;
    int nodeEnd = min(n, (b + 1) << shift);
    int cntNodes = nodeEnd - node0;
    int myBase = lo + lcur[t] - c;  // exclusive prefix within bucket
    if (t < cntNodes) {
        row_ptr[node0 + t] = myBase;
        dinv[node0 + t] = rsqrtf((float)(c + 1));  // +1 self-loop
    }
    if (b == nbuck - 1 && t == 0) row_ptr[n] = E;
    for (int j = t; j < cntNodes * 9; j += 256) {
        int nl = j / 9, f = j - nl * 9;
        float dnl = rsqrtf((float)(cnt[nl] + 1));
        xs[(size_t)(node0 + nl) * 9 + f] = dnl * x[(size_t)(node0 + nl) * 9 + f];
    }
    __syncthreads();
    lcur[t] = myBase;  // running cursors
    __syncthreads();
    for (int e = lo + t; e < hi; e += 256) {
        uint p = binned[e];
        int pos = atomicAdd(&lcur[p >> 24], 1);
        csr[pos] = (int)(p & 0xFFFFFF);
    }
}

// ---------------- Layer 1 aggregate: aggx = dinv .* (sum_s xs[s] + xs[node]) ----------------

__global__ __launch_bounds__(256) void k_agg1(const float* __restrict__ xs,
                       const float* __restrict__ dinv,
                       const int* __restrict__ row_ptr, const int* __restrict__ csr,
                       float* __restrict__ aggx, int n) {
    int node = blockIdx.x * 16 + (threadIdx.x >> 4);
    if (node >= n) return;
    int f = threadIdx.x & 15;
    bool act = f < 9;
    float acc = act ? xs[node * 9 + f] : 0.f;  // self-loop (xs = dinv*x)
    int e0 = row_ptr[node], e1 = row_ptr[node + 1];
    int e = e0;
    for (; e + 4 <= e1; e += 4) {
        int s0 = csr[e], s1 = csr[e + 1], s2 = csr[e + 2], s3 = csr[e + 3];
        float x0 = act ? xs[s0 * 9 + f] : 0.f;
        float x1 = act ? xs[s1 * 9 + f] : 0.f;
        float x2 = act ? xs[s2 * 9 + f] : 0.f;
        float x3 = act ? xs[s3 * 9 + f] : 0.f;
        acc += (x0 + x1) + (x2 + x3);
    }
    for (; e < e1; ++e) {
        int sA = csr[e];
        acc += act ? xs[sA * 9 + f] : 0.f;
    }
    if (act) aggx[node * 9 + f] = dinv[node] * acc;
}

// ---------------- Fused layer1-matmul + layer2 GEMM ----------------
// Round-6 l2mm skeleton (B half in LDS, ONE barrier, 4x4 MFMA reg tile) but the
// A-fragments (h1 rows) are computed just-in-time in registers from aggx (36
// VGPRs/lane) + W1/b1 (L1-resident), bit-identical order to the old k_l1mm.
// Kills the 51MB h1 write + 102MB h1 reads and one dispatch.
__global__ __launch_bounds__(256, 2) void k_l12(const float* __restrict__ aggx,
                       const float* __restrict__ W1, const float* __restrict__ b1,
                       const float* __restrict__ W2, const float* __restrict__ dinv,
                       __hip_bfloat16* __restrict__ t2, int n, int nchunk) {
    __shared__ short bsh[64 * 64 * 8];  // 64 KB: [kb 0..63][c 0..63][j 0..7]
    int t = threadIdx.x;
    int colbase = blockIdx.y << 6;

    for (int idx = t; idx < 64 * 64; idx += 256) {
        int kb = idx >> 6, c = idx & 63;
        const float* wp = W2 + (size_t)(kb * 8) * 128 + colbase + c;
        short8 o;
#pragma unroll
        for (int j = 0; j < 8; ++j) o[j] = f2bf_bits(wp[j * 128]);
        *reinterpret_cast<short8*>(bsh + (size_t)idx * 8) = o;
    }
    __syncthreads();

    int wid = t >> 6, lane = t & 63;
    int chunk = blockIdx.x * 4 + wid;
    if (chunk >= nchunk) return;
    int r = lane & 15, quad = lane >> 4;
    int m0 = chunk << 6;

    // per-lane aggx rows (4 m-tiles); rows >= n read garbage but stay row-contained
    float av[4][9];
#pragma unroll
    for (int mt = 0; mt < 4; ++mt) {
        const float* ap = aggx + (size_t)(m0 + mt * 16 + r) * 9;
        float4 a0 = *(const float4*)ap;
        float4 a1 = *(const float4*)(ap + 4);
        av[mt][0] = a0.x; av[mt][1] = a0.y; av[mt][2] = a0.z; av[mt][3] = a0.w;
        av[mt][4] = a1.x; av[mt][5] = a1.y; av[mt][6] = a1.z; av[mt][7] = a1.w;
        av[mt][8] = ap[8];
    }

    float4v acc[4][4];
#pragma unroll
    for (int mt = 0; mt < 4; ++mt)
#pragma unroll
        for (int cg = 0; cg < 4; ++cg) acc[mt][cg] = (float4v){0, 0, 0, 0};

#pragma unroll
    for (int kt = 0; kt < 16; ++kt) {
        int kb = kt * 32 + quad * 8;
        float4 bb0 = *(const float4*)(b1 + kb);
        float4 bb1 = *(const float4*)(b1 + kb + 4);
        float a8[4][8];
#pragma unroll
        for (int mt = 0; mt < 4; ++mt) {
            a8[mt][0] = bb0.x; a8[mt][1] = bb0.y; a8[mt][2] = bb0.z; a8[mt][3] = bb0.w;
            a8[mt][4] = bb1.x; a8[mt][5] = bb1.y; a8[mt][6] = bb1.z; a8[mt][7] = bb1.w;
        }
#pragma unroll
        for (int f = 0; f < 9; ++f) {
            const float* wp = W1 + f * 512 + kb;
            float4 wa = *(const float4*)wp;
            float4 wb = *(const float4*)(wp + 4);
#pragma unroll
            for (int mt = 0; mt < 4; ++mt) {
                float x = av[mt][f];
                a8[mt][0] += x * wa.x; a8[mt][1] += x * wa.y;
                a8[mt][2] += x * wa.z; a8[mt][3] += x * wa.w;
                a8[mt][4] += x * wb.x; a8[mt][5] += x * wb.y;
                a8[mt][6] += x * wb.z; a8[mt][7] += x * wb.w;
            }
        }
        short8 afr[4];
#pragma unroll
        for (int mt = 0; mt < 4; ++mt)
#pragma unroll
            for (int j = 0; j < 8; ++j)
                afr[mt][j] = f2bf_bits(fmaxf(a8[mt][j], 0.f));

        short8 b[4];
#pragma unroll
        for (int cg = 0; cg < 4; ++cg)
            b[cg] = *reinterpret_cast<const short8*>(
                bsh + (size_t)(((kt * 4 + quad) * 64) + cg * 16 + r) * 8);
#pragma unroll
        for (int mt = 0; mt < 4; ++mt)
#pragma unroll
            for (int cg = 0; cg < 4; ++cg)
                acc[mt][cg] = __builtin_amdgcn_mfma_f32_16x16x32_bf16(afr[mt], b[cg], acc[mt][cg], 0, 0, 0);
    }

    // Epilogue: C/D col = lane&15, row = quad*4 + reg; scale row by dinv[node]
#pragma unroll
    for (int mt = 0; mt < 4; ++mt)
#pragma unroll
        for (int i = 0; i < 4; ++i) {
            int node = m0 + mt * 16 + quad * 4 + i;
            if (node < n) {
                float di = dinv[node];
                __hip_bfloat16* op = t2 + (size_t)node * 128 + colbase + r;
#pragma unroll
                for (int cg = 0; cg < 4; ++cg)
                    op[cg * 16] = __float2bfloat16(di * acc[mt][cg][i]);
            }
        }
}

// ---------------- Layer 2 aggregate + fused layer-3 matmul ----------------

__global__ __launch_bounds__(256) void k_agg2(const uint* __restrict__ t2u,
                       const float* __restrict__ dinv,
                       const int* __restrict__ row_ptr, const int* __restrict__ csr,
                       const float* __restrict__ b2, const float* __restrict__ W3,
                       float2* __restrict__ t3, int n) {
    int node = blockIdx.x * 4 + (threadIdx.x >> 6);
    if (node >= n) return;
    int lane = threadIdx.x & 63;
    float2 p = up_bf2(t2u[(size_t)node * 64 + lane]);  // self (t2' = dinv*t2)
    float a0 = p.x, a1 = p.y;
    int e0 = row_ptr[node], e1 = row_ptr[node + 1];
    int e = e0;
    for (; e + 8 <= e1; e += 8) {
        int si[8];
        uint ri[8];
#pragma unroll
        for (int j = 0; j < 8; ++j) si[j] = csr[e + j];
#pragma unroll
        for (int j = 0; j < 8; ++j) ri[j] = t2u[(size_t)si[j] * 64 + lane];
#pragma unroll
        for (int j = 0; j < 8; ++j) {
            float2 q = up_bf2(ri[j]);
            a0 += q.x;
            a1 += q.y;
        }
    }
    for (; e + 2 <= e1; e += 2) {
        int s0 = csr[e], s1 = csr[e + 1];
        uint r0 = t2u[(size_t)s0 * 64 + lane];
        uint r1 = t2u[(size_t)s1 * 64 + lane];
        float2 q0 = up_bf2(r0), q1 = up_bf2(r1);
        a0 += q0.x + q1.x;
        a1 += q0.y + q1.y;
    }
    if (e < e1) {
        float2 q0 = up_bf2(t2u[(size_t)csr[e] * 64 + lane]);
        a0 += q0.x;
        a1 += q0.y;
    }
    float di = dinv[node];
    float2 bb = *reinterpret_cast<const float2*>(b2 + 2 * lane);
    float h0 = fmaxf(di * a0 + bb.x, 0.f);
    float h1v = fmaxf(di * a1 + bb.y, 0.f);
    float4 wv = *reinterpret_cast<const float4*>(W3 + 4 * lane);
    float c0 = h0 * wv.x + h1v * wv.z;
    float c1 = h0 * wv.y + h1v * wv.w;
#pragma unroll
    for (int off = 32; off; off >>= 1) {
        c0 += __shfl_xor(c0, off);
        c1 += __shfl_xor(c1, off);
    }
    if (lane == 0) t3[node] = make_float2(di * c0, di * c1);  // prescaled
}

// ---------------- Layer 3 aggregate + log_softmax ----------------

__global__ void k_agg3(const float2* __restrict__ t3, const float* __restrict__ dinv,
                       const int* __restrict__ row_ptr, const int* __restrict__ csr,
                       const float* __restrict__ b3, float2* __restrict__ outv, int n) {
    int node = blockIdx.x * blockDim.x + threadIdx.x;
    if (node >= n) return;
    float2 s = t3[node];  // self (t3' = dinv*t3)
    float a0 = s.x, a1 = s.y;
    int e0 = row_ptr[node], e1 = row_ptr[node + 1];
    int e = e0;
    for (; e + 4 <= e1; e += 4) {
        int s0 = csr[e], s1 = csr[e + 1], s2 = csr[e + 2], s3 = csr[e + 3];
        float2 q0 = t3[s0], q1 = t3[s1], q2 = t3[s2], q3 = t3[s3];
        a0 += q0.x + q1.x + q2.x + q3.x;
        a1 += q0.y + q1.y + q2.y + q3.y;
    }
    for (; e < e1; ++e) {
        float2 q0 = t3[csr[e]];
        a0 += q0.x;
        a1 += q0.y;
    }
    float di = dinv[node];
    float z0 = di * a0 + b3[0];
    float z1 = di * a1 + b3[1];
    float m = fmaxf(z0, z1);
    float lse = m + logf(expf(z0 - m) + expf(z1 - m));
    outv[node] = make_float2(z0 - lse, z1 - lse);
}

// ---------------- launch ----------------

extern "C" void kernel_launch(void* const* d_in, const int* in_sizes, int n_in,
                              void* d_out, int out_size, void* d_ws, size_t ws_size,
                              hipStream_t stream) {
    const float* x  = (const float*)d_in[0];
    const float* W1 = (const float*)d_in[1];
    const float* b1 = (const float*)d_in[2];
    const float* W2 = (const float*)d_in[3];
    const float* b2 = (const float*)d_in[4];
    const float* W3 = (const float*)d_in[5];
    const float* b3 = (const float*)d_in[6];
    const int* edges = (const int*)d_in[7];

    int n = in_sizes[0] / 9;
    int E = in_sizes[7] / 2;
    const int* src = edges;
    const int* dst = edges + E;

    char* p = (char*)d_ws;
    auto alloc = [&](size_t bytes) {
        char* q = p;
        p += (bytes + 511) & ~(size_t)511;
        return q;
    };
    float* dinv       = (float*)alloc((size_t)n * 4);
    int*   row_ptr    = (int*)alloc((size_t)(n + 1) * 4);
    int*   csr        = (int*)alloc((size_t)E * 4);
    int*   histBlk    = (int*)alloc((size_t)256 * NBLK * 4);
    int*   baseBlk    = (int*)alloc((size_t)256 * NBLK * 4);
    int*   btot       = (int*)alloc(256 * 4);
    int*   bucketBase = (int*)alloc(256 * 4);
    uint*  binned     = (uint*)alloc((size_t)E * 4);
    float* xs         = (float*)alloc((size_t)n * 9 * 4);
    float* aggx       = (float*)alloc((size_t)(n + 64) * 9 * 4);  // +64 rows OOB-read pad
    __hip_bfloat16* t2 = (__hip_bfloat16*)alloc((size_t)n * 128 * 2);
    float2* t3 = (float2*)alloc((size_t)n * 8);

    const int B = 256;
    int shift = 8;  // packed binned requires shift==8 (dst_local 8b) and n < 2^24
    int nbuck = ((n - 1) >> shift) + 1;
    int chunk = (E + NBLK - 1) / NBLK;

    k_hist<<<NBLK, B, 0, stream>>>(dst, E, chunk, shift, nbuck, histBlk);
    k_btot<<<nbuck, B, 0, stream>>>(histBlk, btot);
    k_bscan<<<nbuck, B, 0, stream>>>(histBlk, btot, nbuck, baseBlk, bucketBase);
    k_scatterbin<<<NBLK, B, 0, stream>>>(src, dst, E, chunk, shift, nbuck, baseBlk, binned);
    k_csrbuild<<<nbuck, B, 0, stream>>>(binned, bucketBase, x, E, shift, n, nbuck,
                                        row_ptr, dinv, xs, csr);

    k_agg1<<<(n + 15) / 16, B, 0, stream>>>(xs, dinv, row_ptr, csr, aggx, n);

    int nchunk = (n + 63) / 64;
    dim3 g2((nchunk + 3) / 4, 2);
    k_l12<<<g2, 256, 0, stream>>>(aggx, W1, b1, W2, dinv, t2, n, nchunk);
    k_agg2<<<(n + 3) / 4, 256, 0, stream>>>((const uint*)t2, dinv, row_ptr, csr, b2, W3, t3, n);

    k_agg3<<<(n + B - 1) / B, B, 0, stream>>>(t3, dinv, row_ptr, csr, b3, (float2*)d_out, n);
}